// Round 2
// baseline (516.668 us; speedup 1.0000x reference)
//
#include <hip/hip_runtime.h>
#include <hip/hip_fp16.h>

// MSAAttention: x = e + PE; q,k,v = Linear(x); out = softmax(q k^T) v
// B=8 S=2048 H=512, fp32 in/out. f16 MFMA GEMMs + fp32-math softmax.
//
// Round 8: NO-LDS flat GEMM (AITER-flatmm pattern). Round 7 post-mortem
// showed the LDS pipe itself was the oversubscribed resource (510 cyc/tile
// LDS reads+DMA-writes vs 310 cyc MFMA, + 3.1M bank conflicts) and barriers
// serialized 4 waves against it. All operands are L2-resident (wcat 1.5MB,
// XCD-sliced A 2MB, per-batch q/k 2+2MB, vt 2MB) so fragments are loaded
// straight global->VGPR in a 2-stage register pipeline; L1 provides the
// intra-block reuse LDS used to. Zero barriers, zero LDS -> residency cap
// lifted, MFMA:issue density up.

using half8   = __attribute__((ext_vector_type(8))) _Float16;
using half4v  = __attribute__((ext_vector_type(4))) _Float16;
using floatx4 = __attribute__((ext_vector_type(4))) float;

// ---- prep (blocks 0..8191): x16 = f16(embeds + PE)
// ---- cvt  (blocks 8192..11263): wcat f16 [1536][512] + bcat fp32 [1536]
__global__ __launch_bounds__(256) void prep_cvt_kernel(const float* __restrict__ e,
                                                       _Float16* __restrict__ x16,
                                                       const float* __restrict__ wq,
                                                       const float* __restrict__ wk,
                                                       const float* __restrict__ wv,
                                                       const float* __restrict__ bq,
                                                       const float* __restrict__ bk,
                                                       const float* __restrict__ bv,
                                                       _Float16* __restrict__ wcat,
                                                       float* __restrict__ bcat) {
  if (blockIdx.x < 8192) {
    int t = blockIdx.x * 256 + threadIdx.x;  // 2M threads, 4 elems each
    int idx = t * 4;
    int h = idx & 511;
    int s = (idx >> 9) & 2047;
    float4 ev = *(const float4*)(e + idx);
    const float ks = -9.210340371976184f / 256.0f;  // -ln(10000)/256
    float r[4] = {ev.x, ev.y, ev.z, ev.w};
#pragma unroll
    for (int j = 0; j < 4; j++) {
      int hh = h + j;
      int i = (hh < 256) ? hh : (hh - 256);
      float ang = (float)s * __expf((float)i * ks);
      r[j] += (hh < 256) ? __sinf(ang) : __cosf(ang);
    }
    half4v o = {(_Float16)r[0], (_Float16)r[1], (_Float16)r[2], (_Float16)r[3]};
    *(half4v*)(x16 + idx) = o;
  } else {
    int i = (blockIdx.x - 8192) * 256 + threadIdx.x;  // 786432
    int m = i & 262143;
    const float* s = (i < 262144) ? wq : (i < 524288) ? wk : wv;
    wcat[i] = (_Float16)s[m];
    if (i < 512) bcat[i] = bq[i];
    else if (i < 1024) bcat[i] = bk[i - 512];
    else if (i < 1536) bcat[i] = bv[i - 1024];
  }
}

// ---- f16 MFMA GEMM, no LDS: C[m][n] = sum_k A[m][k]*B[n][k] ----
// A [M,K] lda, B [N,K] ldb, k-contiguous. Tile BM x 128, 4 waves (2x2),
// wave tile (BM/2) x 64 via 16x16x32 frags. Fragments loaded directly
// global->VGPR (lane (l16,quad) reads 16B at row l16, col quad*8 -- a quad
// covers one full 64B line). 2-stage register pipeline: stage loads (MI+4
// x dwordx4, ~1KB/instr) fly under 16 MFMAs (~310 cyc) > L2 latency.
// MODE 0: plain 3D grid, plain store.
// MODE 1: QKV — 1D grid 1536, XCD decode, epilogue bias + route q/k plain,
//         v transposed.
// MODE 2: 1D grid, XCD decode bz = id&7 (batch->XCD), bx = j & (2^LBX - 1).
template <int BM, typename OutT, int MODE, int LBX>
__global__ __launch_bounds__(256) void gemm8(const _Float16* __restrict__ A,
                                             const _Float16* __restrict__ B,
                                             const float* __restrict__ bias,
                                             OutT* __restrict__ C,
                                             int lda, int ldb, int ldo, int K,
                                             long long sA, long long sB, long long sC,
                                             _Float16* __restrict__ oq,
                                             _Float16* __restrict__ ok,
                                             _Float16* __restrict__ ov) {
  int bx, by, bz;
  if constexpr (MODE == 1) {
    unsigned i = blockIdx.x;           // 1536 blocks
    unsigned c = i & 7, j = i >> 3;    // j in [0,192)
    by = c * 16 + j / 12;              // XCD c owns by-range [16c,16c+16)
    bx = j % 12;
    bz = 0;
  } else if constexpr (MODE == 2) {
    unsigned i = blockIdx.x;
    unsigned c = i & 7, j = i >> 3;
    bz = c;                            // batch -> XCD: operands L2-resident
    bx = j & ((1u << LBX) - 1);
    by = j >> LBX;
  } else {
    bx = blockIdx.x; by = blockIdx.y; bz = blockIdx.z;
  }
  A += (long long)bz * sA;
  B += (long long)bz * sB;
  C += (long long)bz * sC;
  const int m0 = by * BM, n0 = bx * 128;
  const int lane = threadIdx.x & 63, wave = threadIdx.x >> 6;
  constexpr int WM = BM / 2;
  constexpr int MI = WM / 16;
  const int wm = (wave >> 1) * WM, wn = (wave & 1) * 64;
  const int quad = lane >> 4, l16 = lane & 15;

  // per-lane fragment base pointers (16B-aligned: rows are 1KB/4KB/32KB)
  const _Float16* Ap[MI];
  const _Float16* Bp[4];
#pragma unroll
  for (int i = 0; i < MI; i++)
    Ap[i] = A + (long long)(m0 + wm + 16 * i + l16) * lda + quad * 8;
#pragma unroll
  for (int i = 0; i < 4; i++)
    Bp[i] = B + (long long)(n0 + wn + 16 * i + l16) * ldb + quad * 8;

  floatx4 acc[MI][4] = {};
  half8 aX[MI], bX[4], aY[MI], bY[4];  // two named stages (static indexing)

  auto loadX = [&](int k) {
#pragma unroll
    for (int i = 0; i < MI; i++) aX[i] = *(const half8*)(Ap[i] + k);
#pragma unroll
    for (int i = 0; i < 4; i++)  bX[i] = *(const half8*)(Bp[i] + k);
  };
  auto loadY = [&](int k) {
#pragma unroll
    for (int i = 0; i < MI; i++) aY[i] = *(const half8*)(Ap[i] + k);
#pragma unroll
    for (int i = 0; i < 4; i++)  bY[i] = *(const half8*)(Bp[i] + k);
  };
  auto mmX = [&]() {
#pragma unroll
    for (int mi = 0; mi < MI; mi++)
#pragma unroll
      for (int ni = 0; ni < 4; ni++)
        acc[mi][ni] = __builtin_amdgcn_mfma_f32_16x16x32_f16(aX[mi], bX[ni], acc[mi][ni], 0, 0, 0);
  };
  auto mmY = [&]() {
#pragma unroll
    for (int mi = 0; mi < MI; mi++)
#pragma unroll
      for (int ni = 0; ni < 4; ni++)
        acc[mi][ni] = __builtin_amdgcn_mfma_f32_16x16x32_f16(aY[mi], bY[ni], acc[mi][ni], 0, 0, 0);
  };

  // K pipeline: K % 64 == 0 for all shapes here (512 / 2048).
  loadX(0);
  int k0 = 0;
  for (; k0 + 64 < K; k0 += 64) {
    loadY(k0 + 32);   // flies under mmX
    mmX();
    loadX(k0 + 64);   // flies under mmY
    mmY();
  }
  loadY(k0 + 32);     // last pair
  mmX();
  mmY();

  // C/D layout (m89-verified): row(m) = quad*4 + reg, col(n) = lane&15
#pragma unroll
  for (int ni = 0; ni < 4; ni++) {
    const int n = n0 + wn + 16 * ni + l16;
    float bv = 0.0f;
    if constexpr (MODE == 1) bv = bias[n];
#pragma unroll
    for (int mi = 0; mi < MI; mi++) {
      const int mg = m0 + wm + 16 * mi + quad * 4;
#pragma unroll
      for (int rr = 0; rr < 4; rr++) {
        float v = acc[mi][ni][rr] + bv;
        if constexpr (MODE == 1) {
          int m = mg + rr;
          if (n < 512) oq[m * 512 + n] = (_Float16)v;
          else if (n < 1024) ok[m * 512 + (n - 512)] = (_Float16)v;
          else ov[(n - 1024) * 16384 + m] = (_Float16)v;  // V^T
        } else {
          C[(long long)(mg + rr) * ldo + n] = (OutT)v;
        }
      }
    }
  }
}

// ---- softmax over f16 rows of S (2048 wide), fp32 math, f16 in place ----
// One wave per row, shuffle-only reductions. All stores depend on sum (every
// load), so the in-place update is safe.
__global__ __launch_bounds__(256) void softmax_kernel(_Float16* __restrict__ S) {
  const int lane = threadIdx.x & 63;
  const int wave = threadIdx.x >> 6;
  const long long row = (long long)blockIdx.x * 4 + wave;
  _Float16* srow = S + row * 2048;
  float v[32];
  float mx = -3.4e38f;
#pragma unroll
  for (int pass = 0; pass < 4; pass++) {
    half8 f = *(const half8*)(srow + (pass * 64 + lane) * 8);
#pragma unroll
    for (int j = 0; j < 8; j++) {
      float x = (float)f[j];
      v[pass * 8 + j] = x;
      mx = fmaxf(mx, x);
    }
  }
#pragma unroll
  for (int o = 32; o > 0; o >>= 1) mx = fmaxf(mx, __shfl_xor(mx, o));
  float sum = 0.0f;
#pragma unroll
  for (int j = 0; j < 32; j++) {
    v[j] = __expf(v[j] - mx);
    sum += v[j];
  }
#pragma unroll
  for (int o = 32; o > 0; o >>= 1) sum += __shfl_xor(sum, o);
  const float inv = 1.0f / sum;
#pragma unroll
  for (int pass = 0; pass < 4; pass++) {
    half8 o8;
#pragma unroll
    for (int j = 0; j < 8; j++) o8[j] = (_Float16)(v[pass * 8 + j] * inv);
    *(half8*)(srow + (pass * 64 + lane) * 8) = o8;
  }
}

extern "C" void kernel_launch(void* const* d_in, const int* in_sizes, int n_in,
                              void* d_out, int out_size, void* d_ws, size_t ws_size,
                              hipStream_t stream) {
  const float* e  = (const float*)d_in[0];
  const float* Wq = (const float*)d_in[1];
  const float* bq = (const float*)d_in[2];
  const float* Wk = (const float*)d_in[3];
  const float* bk = (const float*)d_in[4];
  const float* Wv = (const float*)d_in[5];
  const float* bv = (const float*)d_in[6];
  float* out = (float*)d_out;
  char* ws = (char*)d_ws;

  const long long MiB = 1024LL * 1024LL;
  // big: S f16 [8][2048][2048] = 64 MiB at once; small: per-batch 8 MiB
  const bool big = ws_size >= (size_t)(115 * MiB);
  const long long base = big ? 64 * MiB : 16 * MiB;  // x16 needs 16 MiB at head

  _Float16* S    = (_Float16*)ws;
  _Float16* x16  = (_Float16*)ws;  // overlays S head; dead before S written
  _Float16* q16  = (_Float16*)(ws + base);
  _Float16* k16  = (_Float16*)(ws + base + 16 * MiB);
  _Float16* vt   = (_Float16*)(ws + base + 32 * MiB);
  _Float16* wcat = (_Float16*)(ws + base + 48 * MiB);   // 1.5 MiB
  float*    bcat = (float*)(ws + base + 48 * MiB + 1536 * 1024);

  prep_cvt_kernel<<<11264, 256, 0, stream>>>(e, x16, Wq, Wk, Wv, bq, bk, bv, wcat, bcat);

  // fused QKV: M=16384 N=1536 K=512; XCD-decoded 1D grid; q/k plain, v transposed
  gemm8<128, _Float16, 1, 0><<<1536, 256, 0, stream>>>(
      x16, wcat, bcat, (_Float16*)nullptr, 512, 512, 0, 512, 0, 0, 0, q16, k16, vt);

  if (big) {
    // S = q k^T batched: M=N=2048 K=512 f16 out; batch->XCD, bx = j&15
    gemm8<128, _Float16, 2, 4><<<2048, 256, 0, stream>>>(
        q16, k16, nullptr, S, 512, 512, 2048, 512,
        1048576LL, 1048576LL, 4194304LL, nullptr, nullptr, nullptr);
    softmax_kernel<<<4096, 256, 0, stream>>>(S);
    // out = P v: BM=64; batch->XCD, bx = j&3
    gemm8<64, float, 2, 2><<<1024, 256, 0, stream>>>(
        S, vt, nullptr, out, 2048, 16384, 512, 2048,
        4194304LL, 2048LL, 1048576LL, nullptr, nullptr, nullptr);
  } else {
    for (int b = 0; b < 8; b++) {
      gemm8<128, _Float16, 0, 0><<<dim3(16, 16, 1), 256, 0, stream>>>(
          q16 + (long long)b * 1048576, k16 + (long long)b * 1048576, nullptr, S,
          512, 512, 2048, 512, 0, 0, 0, nullptr, nullptr, nullptr);
      softmax_kernel<<<512, 256, 0, stream>>>(S);
      gemm8<64, float, 0, 0><<<dim3(4, 32, 1), 256, 0, stream>>>(
          S, vt + (long long)b * 2048, nullptr, out + (long long)b * 1048576,
          2048, 16384, 512, 2048, 0, 0, 0, nullptr, nullptr, nullptr);
    }
  }
}

// Round 3
// 279.510 us; speedup vs baseline: 1.8485x; 1.8485x over previous
//
#include <hip/hip_runtime.h>
#include <hip/hip_fp16.h>

// MSAAttention: x = e + PE; q,k,v = Linear(x); out = softmax(q k^T) v
// B=8 S=2048 H=512, fp32 in/out. f16 MFMA GEMMs + fp32-math softmax.
//
// Round 9: full 8-phase deep-pipelined GEMM (T1+T2+T3+T4+T5 stack, m201
// lineage) replacing the 2-phase gemm6 for QKV / S / PV. 256x256 (128x256
// for PV) tile, BK=64 split into contiguous 16KB K-half-tiles so
// global_load_lds stays linear; one half-tile staged per phase into regions
// provably dead since the previous close-barrier; counted vmcnt(IA+IB) once
// per K-tile (never 0 until the last two tiles); XOR-swizzled LDS reads
// (slot = quad ^ ((l16>>1)&3), conflict-free) with the inverse swizzle
// applied to the per-lane global staging address; setprio(1) around each
// 16-MFMA cluster. gemm6 (proven 2-phase) kept for the small-ws path.

using half8   = __attribute__((ext_vector_type(8))) _Float16;
using half4v  = __attribute__((ext_vector_type(4))) _Float16;
using floatx4 = __attribute__((ext_vector_type(4))) float;

#define VMCNT(N) asm volatile("s_waitcnt vmcnt(" #N ")" ::: "memory")

__device__ __forceinline__ void g2l16(const void* g, void* l) {
  // async global->LDS DMA, 16 B/lane; LDS dest = wave-uniform base + lane*16
  __builtin_amdgcn_global_load_lds((const __attribute__((address_space(1))) void*)g,
                                   (__attribute__((address_space(3))) void*)l, 16, 0, 0);
}

// ---- prep (blocks 0..8191): x16 = f16(embeds + PE)
// ---- cvt  (blocks 8192..11263): wcat f16 [1536][512] + bcat fp32 [1536]
__global__ __launch_bounds__(256) void prep_cvt_kernel(const float* __restrict__ e,
                                                       _Float16* __restrict__ x16,
                                                       const float* __restrict__ wq,
                                                       const float* __restrict__ wk,
                                                       const float* __restrict__ wv,
                                                       const float* __restrict__ bq,
                                                       const float* __restrict__ bk,
                                                       const float* __restrict__ bv,
                                                       _Float16* __restrict__ wcat,
                                                       float* __restrict__ bcat) {
  if (blockIdx.x < 8192) {
    int t = blockIdx.x * 256 + threadIdx.x;  // 2M threads, 4 elems each
    int idx = t * 4;
    int h = idx & 511;
    int s = (idx >> 9) & 2047;
    float4 ev = *(const float4*)(e + idx);
    const float ks = -9.210340371976184f / 256.0f;  // -ln(10000)/256
    float r[4] = {ev.x, ev.y, ev.z, ev.w};
#pragma unroll
    for (int j = 0; j < 4; j++) {
      int hh = h + j;
      int i = (hh < 256) ? hh : (hh - 256);
      float ang = (float)s * __expf((float)i * ks);
      r[j] += (hh < 256) ? __sinf(ang) : __cosf(ang);
    }
    half4v o = {(_Float16)r[0], (_Float16)r[1], (_Float16)r[2], (_Float16)r[3]};
    *(half4v*)(x16 + idx) = o;
  } else {
    int i = (blockIdx.x - 8192) * 256 + threadIdx.x;  // 786432
    int m = i & 262143;
    const float* s = (i < 262144) ? wq : (i < 524288) ? wk : wv;
    wcat[i] = (_Float16)s[m];
    if (i < 512) bcat[i] = bq[i];
    else if (i < 1024) bcat[i] = bk[i - 512];
    else if (i < 1536) bcat[i] = bv[i - 1024];
  }
}

// ---- gemm9: 8-phase deep-pipelined f16 MFMA GEMM ----
// C[m][n] = sum_k A[m][k]*B[n][k]; A [M,K] lda, B [N,K] ldb, k-contiguous.
// Tile BM x BN, BK=64, 8 waves (2M x 4N), per-wave (BM/2) x (BN/4).
// LDS: [2 bufs][2 kk-halves][rows][32 halves]; each kk-half contiguous
// (rows of 64B) so one gload issue (1KB linear) = 16 rows. Swizzle:
// logical col-group q of row r stored at slot q ^ ((r>>1)&3).
// Pipeline: stage slots per tile t: p1=A1[t+1], p2=B1[t+1], p3=A0[t+2],
// p4=B0[t+2]; vmcnt(IA+IB) at p4 (vmcnt(0) for last 2 tiles).
// MODE 1: QKV, 1D grid 384, XCD decode, bias + q/k plain, v transposed.
// MODE 2: 1D grid, bz = id&7 (batch->XCD), bx = j & (2^LBX-1).
template <int BM, int BN, typename OutT, int MODE, int LBX>
__global__ __launch_bounds__(512, 2) void gemm9(const _Float16* __restrict__ A,
                                                const _Float16* __restrict__ B,
                                                const float* __restrict__ bias,
                                                OutT* __restrict__ C,
                                                int lda, int ldb, int ldo, int K,
                                                long long sA, long long sB, long long sC,
                                                _Float16* __restrict__ oq,
                                                _Float16* __restrict__ ok,
                                                _Float16* __restrict__ ov) {
  constexpr int MI = BM / 32;   // per-wave m-frags
  constexpr int NI = BN / 64;   // per-wave n-frags
  constexpr int NIH = NI / 2;
  constexpr int IA = BM / 128;  // gload issues / wave / A-half
  constexpr int IB = BN / 128;

  __shared__ _Float16 Ash[2][2][BM * 32];
  __shared__ _Float16 Bsh[2][2][BN * 32];

  int bx, by, bz;
  if constexpr (MODE == 1) {
    unsigned i = blockIdx.x;         // 384 blocks
    unsigned c = i & 7, j = i >> 3;  // j in [0,48)
    by = c * 8 + (j & 7);            // XCD c owns by-range [8c, 8c+8)
    bx = j >> 3;                     // 0..5
    bz = 0;
  } else {
    unsigned i = blockIdx.x;
    unsigned c = i & 7, j = i >> 3;
    bz = c;                          // batch -> XCD: operands L2-resident
    bx = j & ((1u << LBX) - 1);
    by = j >> LBX;
  }
  A += (long long)bz * sA;
  B += (long long)bz * sB;
  C += (long long)bz * sC;
  const int m0 = by * BM, n0 = bx * BN;
  const int tid = threadIdx.x;
  const int lane = tid & 63, wave = tid >> 6;
  const int l16 = lane & 15, quad = lane >> 4;
  const int wrow = (wave >> 2) * (BM / 2);
  const int wcol = (wave & 3) * (BN / 4);
  const int srow = lane >> 2;                              // staging row in issue
  const int scol = 8 * ((lane & 3) ^ ((lane >> 3) & 3));   // inverse-swizzled col
  const int rsw = (l16 >> 1) & 3;                          // read-side swizzle

  // staging source base pointers (k-invariant)
  const _Float16* aSrc[IA];
  const _Float16* bSrc[IB];
#pragma unroll
  for (int i = 0; i < IA; i++)
    aSrc[i] = A + (long long)(m0 + (wave * IA + i) * 16 + srow) * lda + scol;
#pragma unroll
  for (int i = 0; i < IB; i++)
    bSrc[i] = B + (long long)(n0 + (wave * IB + i) * 16 + srow) * ldb + scol;

  auto stA = [&](int tile, int kk) {
#pragma unroll
    for (int i = 0; i < IA; i++)
      g2l16(aSrc[i] + tile * 64 + kk * 32,
            (_Float16*)Ash[tile & 1][kk] + (wave * IA + i) * 512);
  };
  auto stB = [&](int tile, int kk) {
#pragma unroll
    for (int i = 0; i < IB; i++)
      g2l16(bSrc[i] + tile * 64 + kk * 32,
            (_Float16*)Bsh[tile & 1][kk] + (wave * IB + i) * 512);
  };

  floatx4 acc[MI][NI] = {};
  half8 af[MI], bf[NI];

  auto ldA = [&](int buf, int kk) {
#pragma unroll
    for (int mi = 0; mi < MI; mi++)
      af[mi] = *(const half8*)(Ash[buf][kk] + (wrow + mi * 16 + l16) * 32 + (quad ^ rsw) * 8);
  };
  auto ldB0 = [&](int buf, int kk) {
#pragma unroll
    for (int j = 0; j < NIH; j++)
      bf[j] = *(const half8*)(Bsh[buf][kk] + (wcol + j * 16 + l16) * 32 + (quad ^ rsw) * 8);
  };
  auto ldB1 = [&](int buf, int kk) {
#pragma unroll
    for (int j = 0; j < NIH; j++)
      bf[NIH + j] = *(const half8*)(Bsh[buf][kk] + (wcol + (NIH + j) * 16 + l16) * 32 + (quad ^ rsw) * 8);
  };
  auto mm0 = [&]() {
#pragma unroll
    for (int mi = 0; mi < MI; mi++)
#pragma unroll
      for (int j = 0; j < NIH; j++)
        acc[mi][j] = __builtin_amdgcn_mfma_f32_16x16x32_f16(af[mi], bf[j], acc[mi][j], 0, 0, 0);
  };
  auto mm1 = [&]() {
#pragma unroll
    for (int mi = 0; mi < MI; mi++)
#pragma unroll
      for (int j = 0; j < NIH; j++)
        acc[mi][NIH + j] =
            __builtin_amdgcn_mfma_f32_16x16x32_f16(af[mi], bf[NIH + j], acc[mi][NIH + j], 0, 0, 0);
  };

#define MFMA_SEG(MMX)                                 \
  __builtin_amdgcn_s_barrier();                       \
  asm volatile("s_waitcnt lgkmcnt(0)" ::: "memory");  \
  __builtin_amdgcn_sched_barrier(0);                  \
  __builtin_amdgcn_s_setprio(1);                      \
  MMX();                                              \
  __builtin_amdgcn_s_setprio(0);                      \
  __builtin_amdgcn_sched_barrier(0);                  \
  __builtin_amdgcn_s_barrier();

  const int NT = K / 64;
  // prologue: tile0 complete + tile1 kk0 halves (FIFO order matters)
  stA(0, 0); stB(0, 0); stA(0, 1); stB(0, 1); stA(1, 0); stB(1, 0);
  if constexpr (IA + IB == 4) { VMCNT(4); } else { VMCNT(3); }
  __builtin_amdgcn_s_barrier();

  for (int t = 0; t < NT; ++t) {
    const int buf = t & 1;
    const bool s1 = (t + 1 < NT), s2 = (t + 2 < NT);
    // p1 (kk0, n-lo) | stage A1[t+1] (other buf, region dead since t-1 p4)
    ldA(buf, 0); ldB0(buf, 0);
    if (s1) stA(t + 1, 1);
    MFMA_SEG(mm0);
    // p2 (kk0, n-hi) | stage B1[t+1]
    ldB1(buf, 0);
    if (s1) stB(t + 1, 1);
    MFMA_SEG(mm1);
    // p3 (kk1, n-lo) | stage A0[t+2] (this buf, region dead since p2)
    ldA(buf, 1); ldB0(buf, 1);
    if (s2) stA(t + 2, 0);
    MFMA_SEG(mm0);
    // p4 (kk1, n-hi) | stage B0[t+2]; counted vmcnt covers next tile's reads
    ldB1(buf, 1);
    if (s2) stB(t + 2, 0);
    if (t < NT - 2) {
      if constexpr (IA + IB == 4) { VMCNT(4); } else { VMCNT(3); }
    } else {
      VMCNT(0);
    }
    MFMA_SEG(mm1);
  }
#undef MFMA_SEG

  // C/D layout (m89-verified): row(m) = quad*4 + reg, col(n) = lane&15
#pragma unroll
  for (int ni = 0; ni < NI; ni++) {
    const int n = n0 + wcol + 16 * ni + l16;
    float bv = 0.0f;
    if constexpr (MODE == 1) bv = bias[n];
#pragma unroll
    for (int mi = 0; mi < MI; mi++) {
      const int mg = m0 + wrow + 16 * mi + quad * 4;
#pragma unroll
      for (int rr = 0; rr < 4; rr++) {
        float v = acc[mi][ni][rr] + bv;
        if constexpr (MODE == 1) {
          int m = mg + rr;
          if (n < 512) oq[m * 512 + n] = (_Float16)v;
          else if (n < 1024) ok[m * 512 + (n - 512)] = (_Float16)v;
          else ov[(n - 1024) * 16384 + m] = (_Float16)v;  // V^T
        } else {
          C[(long long)(mg + rr) * ldo + n] = (OutT)v;
        }
      }
    }
  }
}

// ---- gemm6: proven 2-phase GEMM, kept for the small-ws fallback (MODE 0) ----
template <int BM, typename OutT>
__global__ __launch_bounds__(256) void gemm6(const _Float16* __restrict__ A,
                                             const _Float16* __restrict__ B,
                                             OutT* __restrict__ C,
                                             int lda, int ldb, int ldo, int K) {
#define BK6 32
  __shared__ _Float16 Ash[2][BM * BK6];
  __shared__ _Float16 Bsh[2][128 * BK6];
  const int bx = blockIdx.x, by = blockIdx.y;
  const int m0 = by * BM, n0 = bx * 128;
  const int tid = threadIdx.x;
  const int lane = tid & 63, wave = tid >> 6;
  constexpr int WM = BM / 2;
  constexpr int MI = WM / 16;
  constexpr int AIt = BM / 64;
  const int wm = (wave >> 1) * WM, wn = (wave & 1) * 64;
  const int quad = lane >> 4, l16 = lane & 15;
  const int lrow = lane >> 2;
  const int lcol = (lane & 3) * 8;

  floatx4 acc[MI][4] = {};

  auto issue = [&](int buf, int k0) {
#pragma unroll
    for (int t = 0; t < AIt; t++) {
      int is = wave * AIt + t;
      g2l16(A + (long long)(m0 + is * 16 + lrow) * lda + k0 + lcol, &Ash[buf][is * 16 * BK6]);
    }
#pragma unroll
    for (int t = 0; t < 2; t++) {
      int is = wave * 2 + t;
      g2l16(B + (long long)(n0 + is * 16 + lrow) * ldb + k0 + lcol, &Bsh[buf][is * 16 * BK6]);
    }
  };
  auto compute = [&](int buf) {
    half8 af[MI], bfr[4];
#pragma unroll
    for (int i = 0; i < MI; i++)
      af[i] = *(const half8*)&Ash[buf][(wm + 16 * i + l16) * BK6 + quad * 8];
#pragma unroll
    for (int i = 0; i < 4; i++)
      bfr[i] = *(const half8*)&Bsh[buf][(wn + 16 * i + l16) * BK6 + quad * 8];
#pragma unroll
    for (int mi = 0; mi < MI; mi++)
#pragma unroll
      for (int ni = 0; ni < 4; ni++)
        acc[mi][ni] = __builtin_amdgcn_mfma_f32_16x16x32_f16(af[mi], bfr[ni], acc[mi][ni], 0, 0, 0);
  };

  issue(0, 0);
  for (int k0 = 0; k0 < K; k0 += 2 * BK6) {
    __syncthreads();
    if (k0 + BK6 < K) issue(1, k0 + BK6);
    compute(0);
    __syncthreads();
    if (k0 + 2 * BK6 < K) issue(0, k0 + 2 * BK6);
    compute(1);
  }
#pragma unroll
  for (int ni = 0; ni < 4; ni++) {
    const int n = n0 + wn + 16 * ni + l16;
#pragma unroll
    for (int mi = 0; mi < MI; mi++) {
      const int mg = m0 + wm + 16 * mi + quad * 4;
#pragma unroll
      for (int rr = 0; rr < 4; rr++)
        C[(long long)(mg + rr) * ldo + n] = (OutT)acc[mi][ni][rr];
    }
  }
#undef BK6
}

// ---- softmax over f16 rows of S (2048 wide), fp32 math, f16 in place ----
__global__ __launch_bounds__(256) void softmax_kernel(_Float16* __restrict__ S) {
  const int lane = threadIdx.x & 63;
  const int wave = threadIdx.x >> 6;
  const long long row = (long long)blockIdx.x * 4 + wave;
  _Float16* srow = S + row * 2048;
  float v[32];
  float mx = -3.4e38f;
#pragma unroll
  for (int pass = 0; pass < 4; pass++) {
    half8 f = *(const half8*)(srow + (pass * 64 + lane) * 8);
#pragma unroll
    for (int j = 0; j < 8; j++) {
      float x = (float)f[j];
      v[pass * 8 + j] = x;
      mx = fmaxf(mx, x);
    }
  }
#pragma unroll
  for (int o = 32; o > 0; o >>= 1) mx = fmaxf(mx, __shfl_xor(mx, o));
  float sum = 0.0f;
#pragma unroll
  for (int j = 0; j < 32; j++) {
    v[j] = __expf(v[j] - mx);
    sum += v[j];
  }
#pragma unroll
  for (int o = 32; o > 0; o >>= 1) sum += __shfl_xor(sum, o);
  const float inv = 1.0f / sum;
#pragma unroll
  for (int pass = 0; pass < 4; pass++) {
    half8 o8;
#pragma unroll
    for (int j = 0; j < 8; j++) o8[j] = (_Float16)(v[pass * 8 + j] * inv);
    *(half8*)(srow + (pass * 64 + lane) * 8) = o8;
  }
}

extern "C" void kernel_launch(void* const* d_in, const int* in_sizes, int n_in,
                              void* d_out, int out_size, void* d_ws, size_t ws_size,
                              hipStream_t stream) {
  const float* e  = (const float*)d_in[0];
  const float* Wq = (const float*)d_in[1];
  const float* bq = (const float*)d_in[2];
  const float* Wk = (const float*)d_in[3];
  const float* bk = (const float*)d_in[4];
  const float* Wv = (const float*)d_in[5];
  const float* bv = (const float*)d_in[6];
  float* out = (float*)d_out;
  char* ws = (char*)d_ws;

  const long long MiB = 1024LL * 1024LL;
  // big: S f16 [8][2048][2048] = 64 MiB at once; small: per-batch 8 MiB
  const bool big = ws_size >= (size_t)(115 * MiB);
  const long long base = big ? 64 * MiB : 16 * MiB;  // x16 needs 16 MiB at head

  _Float16* S    = (_Float16*)ws;
  _Float16* x16  = (_Float16*)ws;  // overlays S head; dead before S written
  _Float16* q16  = (_Float16*)(ws + base);
  _Float16* k16  = (_Float16*)(ws + base + 16 * MiB);
  _Float16* vt   = (_Float16*)(ws + base + 32 * MiB);
  _Float16* wcat = (_Float16*)(ws + base + 48 * MiB);   // 1.5 MiB
  float*    bcat = (float*)(ws + base + 48 * MiB + 1536 * 1024);

  prep_cvt_kernel<<<11264, 256, 0, stream>>>(e, x16, Wq, Wk, Wv, bq, bk, bv, wcat, bcat);

  // fused QKV: M=16384 N=1536 K=512; 8-phase 256x256; q/k plain, v transposed
  gemm9<256, 256, _Float16, 1, 0><<<384, 512, 0, stream>>>(
      x16, wcat, bcat, (_Float16*)nullptr, 512, 512, 0, 512, 0, 0, 0, q16, k16, vt);

  if (big) {
    // S = q k^T batched: M=N=2048 K=512 f16 out; batch->XCD; 8-phase 256x256
    gemm9<256, 256, _Float16, 2, 3><<<512, 512, 0, stream>>>(
        q16, k16, nullptr, S, 512, 512, 2048, 512,
        1048576LL, 1048576LL, 4194304LL, nullptr, nullptr, nullptr);
    softmax_kernel<<<4096, 256, 0, stream>>>(S);
    // out = P v: M=2048 N=512 K=2048; batch->XCD; 8-phase 128x256
    gemm9<128, 256, float, 2, 1><<<256, 512, 0, stream>>>(
        S, vt, nullptr, out, 2048, 16384, 512, 2048,
        4194304LL, 2048LL, 1048576LL, nullptr, nullptr, nullptr);
  } else {
    for (int b = 0; b < 8; b++) {
      gemm6<128, _Float16><<<dim3(16, 16, 1), 256, 0, stream>>>(
          q16 + (long long)b * 1048576, k16 + (long long)b * 1048576, S,
          512, 512, 2048, 512);
      softmax_kernel<<<512, 256, 0, stream>>>(S);
      gemm6<64, float><<<dim3(4, 32, 1), 256, 0, stream>>>(
          S, vt + (long long)b * 2048, out + (long long)b * 1048576,
          2048, 16384, 512, 2048);
    }
  }
}